// Round 1
// baseline (720.727 us; speedup 1.0000x reference)
//
#include <hip/hip_runtime.h>

// HybridConv: 3×SAGEConv (sum/mean/max aggr) fused.
// Phase 1: edge-parallel atomic scatter-aggregate (sum, max, count).
// Phase 2: per-node 4× (64x64) matvec with weights in LDS, activations
//          broadcast via v_readlane.
// seg_sum aliases d_out (each element read-then-written by the same thread).

#define NN 100000
#define NE 1000000
#define CC 64
#define CBLK 512
#define MPW 4  // nodes per wave per iteration

__device__ __forceinline__ float bcastf(float v, int l) {
  return __int_as_float(__builtin_amdgcn_readlane(__float_as_int(v), l));
}

__global__ __launch_bounds__(256) void init_kernel(float* __restrict__ seg_sum,
                                                   int* __restrict__ seg_max,
                                                   float* __restrict__ cnt) {
  int stride = gridDim.x * blockDim.x;
  int i0 = blockIdx.x * blockDim.x + threadIdx.x;
  for (int i = i0; i < NN * CC; i += stride) {
    seg_sum[i] = 0.0f;
    seg_max[i] = (int)0xFF800000;  // -inf bits
  }
  for (int i = i0; i < NN; i += stride) cnt[i] = 0.0f;
}

__global__ __launch_bounds__(256) void wsum_kernel(const float* __restrict__ W_r,
                                                   const float* __restrict__ b,
                                                   float* __restrict__ Wr_sum,
                                                   float* __restrict__ b_sum) {
  int i = blockIdx.x * blockDim.x + threadIdx.x;
  if (i < CC * CC) Wr_sum[i] = W_r[i] + W_r[CC * CC + i] + W_r[2 * CC * CC + i];
  if (i < CC) b_sum[i] = b[i] + b[CC + i] + b[2 * CC + i];
}

__global__ __launch_bounds__(256) void aggregate_kernel(const float* __restrict__ x,
                                                        const int* __restrict__ ei,
                                                        float* __restrict__ seg_sum,
                                                        int* __restrict__ seg_max,
                                                        float* __restrict__ cnt) {
  unsigned long long t = (unsigned long long)blockIdx.x * blockDim.x + threadIdx.x;
  int e = (int)(t >> 6);
  int c = (int)(t & 63);
  int s = ei[e];
  int d = ei[NE + e];
  float val = x[s * CC + c];
  atomicAdd(&seg_sum[d * CC + c], val);
  int* mp = &seg_max[d * CC + c];
  if (val >= 0.0f) {
    atomicMax(mp, __float_as_int(val));
  } else {
    atomicMin((unsigned int*)mp, __float_as_uint(val));
  }
  if (c == 0) atomicAdd(&cnt[d], 1.0f);
}

__global__ __launch_bounds__(CBLK) void combine_kernel(const float* __restrict__ x,
                                                       const float* seg_sum,  // aliases out
                                                       const int* __restrict__ seg_max,
                                                       const float* __restrict__ cnt,
                                                       const float* __restrict__ W_l,
                                                       const float* __restrict__ Wr_sum,
                                                       const float* __restrict__ b_sum,
                                                       float* out) {
  __shared__ float Ws[4 * CC * CC];  // 64 KB exactly: W_l0, W_l1, W_l2, Wr_sum
  int tid = threadIdx.x;
  const float4* wl4 = (const float4*)W_l;
  const float4* wr4 = (const float4*)Wr_sum;
  float4* ws4 = (float4*)Ws;
  for (int i = tid; i < 3 * CC * CC / 4; i += CBLK) ws4[i] = wl4[i];
  for (int i = tid; i < CC * CC / 4; i += CBLK) ws4[3 * CC * CC / 4 + i] = wr4[i];
  __syncthreads();

  int lane = tid & 63;
  int wv = tid >> 6;                        // wave within block (0..7)
  int nwaves = (gridDim.x * CBLK) >> 6;     // total waves
  int gw = blockIdx.x * (CBLK >> 6) + wv;   // global wave id
  float breg = b_sum[lane];

  const float* W0 = Ws;
  const float* W1 = Ws + CC * CC;
  const float* W2 = Ws + 2 * CC * CC;
  const float* W3 = Ws + 3 * CC * CC;

  for (int nb = gw * MPW; nb < NN; nb += nwaves * MPW) {
    float sv[MPW], a1[MPW], a2[MPW], xv[MPW], acc[MPW];
#pragma unroll
    for (int k = 0; k < MPW; ++k) {
      int n = nb + k;  // NN % MPW == 0, always in range
      float ss = seg_sum[n * CC + lane];
      float mb = __int_as_float(seg_max[n * CC + lane]);
      float cn = cnt[n];
      sv[k] = ss;
      a1[k] = ss * (1.0f / fmaxf(cn, 1.0f));
      a2[k] = cn > 0.0f ? mb : 0.0f;
      xv[k] = x[n * CC + lane];
      acc[k] = breg;
    }
#pragma unroll
    for (int c = 0; c < CC; ++c) {
      float w0 = W0[c * CC + lane];
      float w1 = W1[c * CC + lane];
      float w2 = W2[c * CC + lane];
      float w3 = W3[c * CC + lane];
#pragma unroll
      for (int k = 0; k < MPW; ++k) {
        acc[k] = fmaf(bcastf(sv[k], c), w0, acc[k]);
        acc[k] = fmaf(bcastf(a1[k], c), w1, acc[k]);
        acc[k] = fmaf(bcastf(a2[k], c), w2, acc[k]);
        acc[k] = fmaf(bcastf(xv[k], c), w3, acc[k]);
      }
    }
#pragma unroll
    for (int k = 0; k < MPW; ++k) out[(nb + k) * CC + lane] = acc[k];
  }
}

extern "C" void kernel_launch(void* const* d_in, const int* in_sizes, int n_in,
                              void* d_out, int out_size, void* d_ws, size_t ws_size,
                              hipStream_t stream) {
  const float* x = (const float*)d_in[0];
  const int* ei = (const int*)d_in[1];
  const float* W_l = (const float*)d_in[2];
  const float* W_r = (const float*)d_in[3];
  const float* b = (const float*)d_in[4];
  float* out = (float*)d_out;

  // Workspace layout (floats): seg_max[NN*CC] (int bits), cnt[NN],
  // Wr_sum[CC*CC], b_sum[CC].  seg_sum lives in d_out.
  float* seg_sum = out;
  int* seg_max = (int*)d_ws;
  float* cnt = (float*)d_ws + (size_t)NN * CC;
  float* Wr_sum = cnt + NN;
  float* b_sum = Wr_sum + CC * CC;

  init_kernel<<<2048, 256, 0, stream>>>(seg_sum, seg_max, cnt);
  wsum_kernel<<<16, 256, 0, stream>>>(W_r, b, Wr_sum, b_sum);
  aggregate_kernel<<<(NE * CC) / 256, 256, 0, stream>>>(x, ei, seg_sum, seg_max, cnt);
  combine_kernel<<<512, CBLK, 0, stream>>>(x, seg_sum, seg_max, cnt, W_l, Wr_sum, b_sum, out);
}

// Round 2
// 460.932 us; speedup vs baseline: 1.5636x; 1.5636x over previous
//
#include <hip/hip_runtime.h>

// HybridConv: 3×SAGEConv (sum/mean/max aggr) fused.
// Round 2: replace 128M-atomic scatter-aggregate with device-built CSR
// (histogram -> 2-level scan -> scatter) + one fused kernel that gathers
// x[src] per node (registers), computes sum/mean/max, and does the 4x
// 64x64 matvec with weights in LDS. No large intermediates.

#define NN 100000
#define NE 1000000
#define CC 64
#define SB 512                    // scan block size
#define NB1 ((NN + SB - 1) / SB)  // 196 scan blocks
#define FBLK 512                  // fused kernel block size
#define MPW 4                     // nodes per wave per iteration

__device__ __forceinline__ float bcastf(float v, int l) {
  return __int_as_float(__builtin_amdgcn_readlane(__float_as_int(v), l));
}

__global__ __launch_bounds__(256) void zero_deg_kernel(int* __restrict__ deg) {
  int i = blockIdx.x * blockDim.x + threadIdx.x;
  if (i < NN) deg[i] = 0;
}

__global__ __launch_bounds__(256) void hist_kernel(const int* __restrict__ ei,
                                                   int* __restrict__ deg) {
  int e = blockIdx.x * blockDim.x + threadIdx.x;
  if (e < NE) atomicAdd(&deg[ei[NE + e]], 1);
}

__global__ __launch_bounds__(256) void wsum_kernel(const float* __restrict__ W_r,
                                                   const float* __restrict__ b,
                                                   float* __restrict__ Wr_sum,
                                                   float* __restrict__ b_sum) {
  int i = blockIdx.x * blockDim.x + threadIdx.x;
  if (i < CC * CC) Wr_sum[i] = W_r[i] + W_r[CC * CC + i] + W_r[2 * CC * CC + i];
  if (i < CC) b_sum[i] = b[i] + b[CC + i] + b[2 * CC + i];
}

// Per-block inclusive scan of deg -> excl (exclusive within block) + block sums.
__global__ __launch_bounds__(SB) void scan1_kernel(const int* __restrict__ deg,
                                                   int* __restrict__ excl,
                                                   int* __restrict__ bsum) {
  __shared__ int sd[SB];
  int tid = threadIdx.x;
  int i = blockIdx.x * SB + tid;
  int v = (i < NN) ? deg[i] : 0;
  sd[tid] = v;
  __syncthreads();
  int acc = v;
  for (int of = 1; of < SB; of <<= 1) {
    int t = (tid >= of) ? sd[tid - of] : 0;
    __syncthreads();
    acc += t;
    sd[tid] = acc;
    __syncthreads();
  }
  if (i < NN) excl[i] = acc - v;
  if (tid == SB - 1) bsum[blockIdx.x] = acc;
}

// Exclusive scan of the NB1 block sums (single block).
__global__ __launch_bounds__(256) void scan2_kernel(const int* __restrict__ bsum,
                                                    int* __restrict__ bofs) {
  __shared__ int sd[256];
  int tid = threadIdx.x;
  int v = (tid < NB1) ? bsum[tid] : 0;
  sd[tid] = v;
  __syncthreads();
  int acc = v;
  for (int of = 1; of < 256; of <<= 1) {
    int t = (tid >= of) ? sd[tid - of] : 0;
    __syncthreads();
    acc += t;
    sd[tid] = acc;
    __syncthreads();
  }
  if (tid < NB1) bofs[tid] = acc - v;
}

__global__ __launch_bounds__(SB) void scan3_kernel(const int* __restrict__ excl,
                                                   const int* __restrict__ bofs,
                                                   int* __restrict__ offs,
                                                   int* __restrict__ cur) {
  int i = blockIdx.x * SB + threadIdx.x;
  if (i < NN) {
    int o = excl[i] + bofs[blockIdx.x];
    offs[i] = o;
    cur[i] = o;
  }
}

__global__ __launch_bounds__(256) void scatter_kernel(const int* __restrict__ ei,
                                                      int* __restrict__ cur,
                                                      int* __restrict__ srcs) {
  int e = blockIdx.x * blockDim.x + threadIdx.x;
  if (e < NE) {
    int s = ei[e];
    int d = ei[NE + e];
    int p = atomicAdd(&cur[d], 1);
    srcs[p] = s;
  }
}

// Fused: per node, gather x[src] rows over its CSR edge list (lane = channel),
// accumulate sum/max in registers, then 4x (64x64) matvec with weights in LDS.
__global__ __launch_bounds__(FBLK) void fused_kernel(const float* __restrict__ x,
                                                     const int* __restrict__ srcs,
                                                     const int* __restrict__ offs,
                                                     const int* __restrict__ deg,
                                                     const float* __restrict__ W_l,
                                                     const float* __restrict__ Wr_sum,
                                                     const float* __restrict__ b_sum,
                                                     float* __restrict__ out) {
  __shared__ float Ws[4 * CC * CC];  // 64 KB: W_l0, W_l1, W_l2, Wr_sum
  int tid = threadIdx.x;
  {
    const float4* wl4 = (const float4*)W_l;
    const float4* wr4 = (const float4*)Wr_sum;
    float4* ws4 = (float4*)Ws;
    for (int i = tid; i < 3 * CC * CC / 4; i += FBLK) ws4[i] = wl4[i];
    for (int i = tid; i < CC * CC / 4; i += FBLK) ws4[3 * CC * CC / 4 + i] = wr4[i];
  }
  __syncthreads();

  int lane = tid & 63;
  int wv = tid >> 6;
  int nwaves = (gridDim.x * FBLK) >> 6;
  int gw = blockIdx.x * (FBLK >> 6) + wv;
  float breg = b_sum[lane];

  const float* W0 = Ws;
  const float* W1 = Ws + CC * CC;
  const float* W2 = Ws + 2 * CC * CC;
  const float* W3 = Ws + 3 * CC * CC;

  for (int nb = gw * MPW; nb < NN; nb += nwaves * MPW) {
    float sv[MPW], a1[MPW], a2[MPW], xv[MPW], acc[MPW];
#pragma unroll
    for (int k = 0; k < MPW; ++k) {
      int n = nb + k;  // NN % MPW == 0
      int o = offs[n];
      int dg = deg[n];
      float sum = 0.0f;
      float mx = -3.402823466e+38f;
      for (int j = 0; j < dg; j += 64) {
        int nrem = dg - j;
        if (nrem > 64) nrem = 64;
        int sidx = 0;
        if (lane < nrem) sidx = srcs[o + j + lane];
        for (int t = 0; t < nrem; ++t) {
          int s = __builtin_amdgcn_readlane(sidx, t);
          float v = x[s * CC + lane];
          sum += v;
          mx = fmaxf(mx, v);
        }
      }
      sv[k] = sum;
      a1[k] = sum * (1.0f / fmaxf((float)dg, 1.0f));
      a2[k] = (dg > 0) ? mx : 0.0f;
      xv[k] = x[n * CC + lane];
      acc[k] = breg;
    }
#pragma unroll
    for (int c = 0; c < CC; ++c) {
      float w0 = W0[c * CC + lane];
      float w1 = W1[c * CC + lane];
      float w2 = W2[c * CC + lane];
      float w3 = W3[c * CC + lane];
#pragma unroll
      for (int k = 0; k < MPW; ++k) {
        acc[k] = fmaf(bcastf(sv[k], c), w0, acc[k]);
        acc[k] = fmaf(bcastf(a1[k], c), w1, acc[k]);
        acc[k] = fmaf(bcastf(a2[k], c), w2, acc[k]);
        acc[k] = fmaf(bcastf(xv[k], c), w3, acc[k]);
      }
    }
#pragma unroll
    for (int k = 0; k < MPW; ++k) out[(nb + k) * CC + lane] = acc[k];
  }
}

extern "C" void kernel_launch(void* const* d_in, const int* in_sizes, int n_in,
                              void* d_out, int out_size, void* d_ws, size_t ws_size,
                              hipStream_t stream) {
  const float* x = (const float*)d_in[0];
  const int* ei = (const int*)d_in[1];
  const float* W_l = (const float*)d_in[2];
  const float* W_r = (const float*)d_in[3];
  const float* b = (const float*)d_in[4];
  float* out = (float*)d_out;

  // Workspace layout (4B units):
  int* deg = (int*)d_ws;          // [NN]
  int* excl = deg + NN;           // [NN]
  int* bsum = excl + NN;          // [NB1]
  int* bofs = bsum + NB1;         // [NB1]
  int* offs = bofs + NB1;         // [NN]
  int* cur = offs + NN;           // [NN]
  int* srcs = cur + NN;           // [NE]
  float* Wr_sum = (float*)(srcs + NE);  // [CC*CC]
  float* b_sum = Wr_sum + CC * CC;      // [CC]

  zero_deg_kernel<<<(NN + 255) / 256, 256, 0, stream>>>(deg);
  hist_kernel<<<(NE + 255) / 256, 256, 0, stream>>>(ei, deg);
  wsum_kernel<<<16, 256, 0, stream>>>(W_r, b, Wr_sum, b_sum);
  scan1_kernel<<<NB1, SB, 0, stream>>>(deg, excl, bsum);
  scan2_kernel<<<1, 256, 0, stream>>>(bsum, bofs);
  scan3_kernel<<<NB1, SB, 0, stream>>>(excl, bofs, offs, cur);
  scatter_kernel<<<(NE + 255) / 256, 256, 0, stream>>>(ei, cur, srcs);
  fused_kernel<<<512, FBLK, 0, stream>>>(x, srcs, offs, deg, W_l, Wr_sum, b_sum, out);
}

// Round 3
// 353.790 us; speedup vs baseline: 2.0372x; 1.3028x over previous
//
#include <hip/hip_runtime.h>

// HybridConv: 3×SAGEConv (sum/mean/max aggr) fused.
// Round 3: software-pipeline the CSR gather 8-deep (loads batched & in
// flight before the accumulate chain) to fix the latency-bound gather seen
// in round 2 (VALUBusy 30%, hbm 9%). Also merged zero_deg+wsum into prep.

#define NN 100000
#define NE 1000000
#define CC 64
#define SB 512                    // scan block size
#define NB1 ((NN + SB - 1) / SB)  // 196 scan blocks
#define FBLK 512                  // fused kernel block size
#define MPW 4                     // nodes per wave per iteration
#define PIPE 8                    // gather pipeline depth

__device__ __forceinline__ float bcastf(float v, int l) {
  return __int_as_float(__builtin_amdgcn_readlane(__float_as_int(v), l));
}

__global__ __launch_bounds__(256) void prep_kernel(int* __restrict__ deg,
                                                   const float* __restrict__ W_r,
                                                   const float* __restrict__ b,
                                                   float* __restrict__ Wr_sum,
                                                   float* __restrict__ b_sum) {
  int i = blockIdx.x * blockDim.x + threadIdx.x;
  if (i < NN) deg[i] = 0;
  if (i < CC * CC) Wr_sum[i] = W_r[i] + W_r[CC * CC + i] + W_r[2 * CC * CC + i];
  if (i < CC) b_sum[i] = b[i] + b[CC + i] + b[2 * CC + i];
}

__global__ __launch_bounds__(256) void hist_kernel(const int* __restrict__ ei,
                                                   int* __restrict__ deg) {
  int e = blockIdx.x * blockDim.x + threadIdx.x;
  if (e < NE) atomicAdd(&deg[ei[NE + e]], 1);
}

// Per-block inclusive scan of deg -> excl (exclusive within block) + block sums.
__global__ __launch_bounds__(SB) void scan1_kernel(const int* __restrict__ deg,
                                                   int* __restrict__ excl,
                                                   int* __restrict__ bsum) {
  __shared__ int sd[SB];
  int tid = threadIdx.x;
  int i = blockIdx.x * SB + tid;
  int v = (i < NN) ? deg[i] : 0;
  sd[tid] = v;
  __syncthreads();
  int acc = v;
  for (int of = 1; of < SB; of <<= 1) {
    int t = (tid >= of) ? sd[tid - of] : 0;
    __syncthreads();
    acc += t;
    sd[tid] = acc;
    __syncthreads();
  }
  if (i < NN) excl[i] = acc - v;
  if (tid == SB - 1) bsum[blockIdx.x] = acc;
}

// Exclusive scan of the NB1 block sums (single block).
__global__ __launch_bounds__(256) void scan2_kernel(const int* __restrict__ bsum,
                                                    int* __restrict__ bofs) {
  __shared__ int sd[256];
  int tid = threadIdx.x;
  int v = (tid < NB1) ? bsum[tid] : 0;
  sd[tid] = v;
  __syncthreads();
  int acc = v;
  for (int of = 1; of < 256; of <<= 1) {
    int t = (tid >= of) ? sd[tid - of] : 0;
    __syncthreads();
    acc += t;
    sd[tid] = acc;
    __syncthreads();
  }
  if (tid < NB1) bofs[tid] = acc - v;
}

__global__ __launch_bounds__(SB) void scan3_kernel(const int* __restrict__ excl,
                                                   const int* __restrict__ bofs,
                                                   int* __restrict__ offs,
                                                   int* __restrict__ cur) {
  int i = blockIdx.x * SB + threadIdx.x;
  if (i < NN) {
    int o = excl[i] + bofs[blockIdx.x];
    offs[i] = o;
    cur[i] = o;
  }
}

__global__ __launch_bounds__(256) void scatter_kernel(const int* __restrict__ ei,
                                                      int* __restrict__ cur,
                                                      int* __restrict__ srcs) {
  int e = blockIdx.x * blockDim.x + threadIdx.x;
  if (e < NE) {
    int s = ei[e];
    int d = ei[NE + e];
    int p = atomicAdd(&cur[d], 1);
    srcs[p] = s;
  }
}

// Fused: per node, gather x[src] rows over its CSR edge list (lane = channel),
// 8-deep pipelined, accumulate sum/max in registers, then 4x (64x64) matvec
// with weights in LDS.
__global__ __launch_bounds__(FBLK, 4) void fused_kernel(const float* __restrict__ x,
                                                        const int* __restrict__ srcs,
                                                        const int* __restrict__ offs,
                                                        const int* __restrict__ deg,
                                                        const float* __restrict__ W_l,
                                                        const float* __restrict__ Wr_sum,
                                                        const float* __restrict__ b_sum,
                                                        float* __restrict__ out) {
  __shared__ float Ws[4 * CC * CC];  // 64 KB: W_l0, W_l1, W_l2, Wr_sum
  int tid = threadIdx.x;
  {
    const float4* wl4 = (const float4*)W_l;
    const float4* wr4 = (const float4*)Wr_sum;
    float4* ws4 = (float4*)Ws;
    for (int i = tid; i < 3 * CC * CC / 4; i += FBLK) ws4[i] = wl4[i];
    for (int i = tid; i < CC * CC / 4; i += FBLK) ws4[3 * CC * CC / 4 + i] = wr4[i];
  }
  __syncthreads();

  int lane = tid & 63;
  int wv = tid >> 6;
  int nwaves = (gridDim.x * FBLK) >> 6;
  int gw = blockIdx.x * (FBLK >> 6) + wv;
  float breg = b_sum[lane];

  const float* W0 = Ws;
  const float* W1 = Ws + CC * CC;
  const float* W2 = Ws + 2 * CC * CC;
  const float* W3 = Ws + 3 * CC * CC;

  for (int nb = gw * MPW; nb < NN; nb += nwaves * MPW) {
    float sv[MPW], a1[MPW], a2[MPW], xv[MPW], acc[MPW];
#pragma unroll
    for (int k = 0; k < MPW; ++k) {
      int n = nb + k;  // NN % MPW == 0
      int o = offs[n];
      int dg = deg[n];
      float sum = 0.0f;
      float mx = -3.402823466e+38f;
      for (int j = 0; j < dg; j += 64) {
        int nrem = dg - j;
        if (nrem > 64) nrem = 64;
        int sidx = srcs[o + j + (lane < nrem ? lane : nrem - 1)];
        for (int t0 = 0; t0 < nrem; t0 += PIPE) {
          float v[PIPE];
#pragma unroll
          for (int p = 0; p < PIPE; ++p) {
            int tt = t0 + p;
            if (tt >= nrem) tt = nrem - 1;  // clamp: loads unconditional
            int s = __builtin_amdgcn_readlane(sidx, tt);
            v[p] = x[s * CC + lane];
          }
#pragma unroll
          for (int p = 0; p < PIPE; ++p) {
            if (t0 + p < nrem) {
              sum += v[p];
              mx = fmaxf(mx, v[p]);
            }
          }
        }
      }
      sv[k] = sum;
      a1[k] = sum * (1.0f / fmaxf((float)dg, 1.0f));
      a2[k] = (dg > 0) ? mx : 0.0f;
      xv[k] = x[n * CC + lane];
      acc[k] = breg;
    }
#pragma unroll
    for (int c = 0; c < CC; ++c) {
      float w0 = W0[c * CC + lane];
      float w1 = W1[c * CC + lane];
      float w2 = W2[c * CC + lane];
      float w3 = W3[c * CC + lane];
#pragma unroll
      for (int k = 0; k < MPW; ++k) {
        acc[k] = fmaf(bcastf(sv[k], c), w0, acc[k]);
        acc[k] = fmaf(bcastf(a1[k], c), w1, acc[k]);
        acc[k] = fmaf(bcastf(a2[k], c), w2, acc[k]);
        acc[k] = fmaf(bcastf(xv[k], c), w3, acc[k]);
      }
    }
#pragma unroll
    for (int k = 0; k < MPW; ++k) out[(nb + k) * CC + lane] = acc[k];
  }
}

extern "C" void kernel_launch(void* const* d_in, const int* in_sizes, int n_in,
                              void* d_out, int out_size, void* d_ws, size_t ws_size,
                              hipStream_t stream) {
  const float* x = (const float*)d_in[0];
  const int* ei = (const int*)d_in[1];
  const float* W_l = (const float*)d_in[2];
  const float* W_r = (const float*)d_in[3];
  const float* b = (const float*)d_in[4];
  float* out = (float*)d_out;

  // Workspace layout (4B units):
  int* deg = (int*)d_ws;          // [NN]
  int* excl = deg + NN;           // [NN]
  int* bsum = excl + NN;          // [NB1]
  int* bofs = bsum + NB1;         // [NB1]
  int* offs = bofs + NB1;         // [NN]
  int* cur = offs + NN;           // [NN]
  int* srcs = cur + NN;           // [NE]
  float* Wr_sum = (float*)(srcs + NE);  // [CC*CC]
  float* b_sum = Wr_sum + CC * CC;      // [CC]

  prep_kernel<<<(NN + 255) / 256, 256, 0, stream>>>(deg, W_r, b, Wr_sum, b_sum);
  hist_kernel<<<(NE + 255) / 256, 256, 0, stream>>>(ei, deg);
  scan1_kernel<<<NB1, SB, 0, stream>>>(deg, excl, bsum);
  scan2_kernel<<<1, 256, 0, stream>>>(bsum, bofs);
  scan3_kernel<<<NB1, SB, 0, stream>>>(excl, bofs, offs, cur);
  scatter_kernel<<<(NE + 255) / 256, 256, 0, stream>>>(ei, cur, srcs);
  fused_kernel<<<512, FBLK, 0, stream>>>(x, srcs, offs, deg, W_l, Wr_sum, b_sum, out);
}